// Round 7
// baseline (2483.091 us; speedup 1.0000x reference)
//
#include <hip/hip_runtime.h>
#include <cstdint>

// ---------------------------------------------------------------------------
// WindowAttention: pad 96->100, roll(+2,+2), 4x4 windows, MHA(8 heads,d=64),
// un-window, roll back, crop. WINDOW-MAJOR token order:
//   m = (g*625 + (hh/4)*25 + (ww/4))*16 + (hh%4)*4 + (ww%4)
// Pipeline (single pass, Mg=160000):
//   gather -> qkv GEMM (persistent-weight streaming) -> window attn
//   -> out GEMM (persistent-weight streaming, fused NCHW scatter)
// GEMM structure: weight slice [128 x 512] lives in LDS for the whole block
// (one barrier total); tokens stream through registers; no main-loop
// barriers / LDS writes / waitcnt asm. W-frag (LDS) is the MFMA A-operand,
// X-frag (regs) the B-operand => D[col, tok]: lane holds 4 consecutive cols.
// ---------------------------------------------------------------------------

typedef __attribute__((ext_vector_type(8))) __bf16 bf16x8;
typedef __attribute__((ext_vector_type(8))) uint16_t u16x8;
typedef __attribute__((ext_vector_type(4))) float f32x4;

__device__ __forceinline__ uint16_t f2bf(float f) {
  union { float f; uint32_t u; } c; c.f = f;
  uint32_t r = c.u + 0x7FFFu + ((c.u >> 16) & 1u);  // RNE
  return (uint16_t)(r >> 16);
}
__device__ __forceinline__ float bf2f(uint16_t u) {
  union { uint32_t u; float f; } c; c.u = ((uint32_t)u) << 16;
  return c.f;
}

__device__ __forceinline__ void g2lds16(const void* g, void* lds) {
  __builtin_amdgcn_global_load_lds(
      (const __attribute__((address_space(1))) uint32_t*)(uintptr_t)g,
      (__attribute__((address_space(3))) uint32_t*)(uintptr_t)lds,
      16, 0, 0);
}

// ---------------------------------------------------------------------------
__global__ void cvt_weights(const float* __restrict__ w1, const float* __restrict__ w2,
                            uint16_t* __restrict__ o1, uint16_t* __restrict__ o2) {
  int i = blockIdx.x * 256 + threadIdx.x;
  if (i < 786432) o1[i] = f2bf(w1[i]);
  if (i < 262144) o2[i] = f2bf(w2[i]);
}

// ---------------------------------------------------------------------------
// Gather: x (NCHW fp32) -> window-major token-major bf16 X[m,512].
// ---------------------------------------------------------------------------
__global__ __launch_bounds__(256) void gather_kernel(
    const float* __restrict__ x, uint16_t* __restrict__ xbf, int n0) {
  __shared__ float tile[64][65];
  const int z = blockIdx.z;
  const int g = z / 100, hh = z % 100;
  const int c0 = blockIdx.y * 64, ww0 = blockIdx.x * 64;
  const int n = n0 + g;
  const int hp = (hh >= 2) ? hh - 2 : hh + 98;
  const bool hok = hp < 96;
  const int t = threadIdx.x;
  const int lane = t & 63, grp = t >> 6;

  const int ww = ww0 + lane;
  const int wp = (ww >= 2) ? ww - 2 : ww + 98;
  const bool wok = hok && (ww < 100) && (wp < 96);
  const float* xb = x + ((size_t)n * 512) * 9216 + (size_t)hp * 96 + wp;
#pragma unroll
  for (int i = 0; i < 16; ++i) {
    int c = grp + i * 4;
    tile[c][lane] = wok ? xb[(size_t)(c0 + c) * 9216] : 0.f;
  }
  __syncthreads();
#pragma unroll
  for (int i = 0; i < 16; ++i) {
    int wl = grp + i * 4;
    int www = ww0 + wl;
    if (www < 100) {
      int m = (g * 625 + (hh >> 2) * 25 + (www >> 2)) * 16 + (hh & 3) * 4 + (www & 3);
      xbf[(size_t)m * 512 + c0 + lane] = f2bf(tile[lane][wl]);
    }
  }
}

// ---------------------------------------------------------------------------
// Persistent-weight streaming GEMM.
//   W: row-major [NS*128, 512] bf16 (K contiguous). Block owns slice sl
//   (128 rows of W = 128 output cols) resident in LDS, XOR-swizzled
//   (byte ^= (row&7)<<4) via pre-swizzled global source (rule #21).
//   X: [160000, 512] bf16. 8 waves x 32 tokens/chunk => 256 tokens/chunk,
//   625 chunks total, split into segments of CPS chunks per block.
//   D[col, tok] = sum_k W[col,k] X[tok,k] (+bias[col]).
//   MFMA: mfma(wfrag, xfrag): D col-quad = lg*4+rr, token = lr.
// EPI 0 (qkv): packed 4x bf16 (8B) stores to Cbf[tok*1536 + col].
// EPI 1 (out): predicated fp32 scatter to (N,C,96,96) with crop.
// ---------------------------------------------------------------------------
template <int EPI, int NS, int CPS>
__global__ __launch_bounds__(512, 2) void gemmP(
    const uint16_t* __restrict__ X, const uint16_t* __restrict__ W,
    const float* __restrict__ bias, uint16_t* __restrict__ Cbf,
    float* __restrict__ Cout) {
  __shared__ alignas(16) uint16_t lds[65536];  // 128 KB: [128 rows][512 k]
  const int t = threadIdx.x;
  const int wv = t >> 6, lane = t & 63;
  const int lr = lane & 15, lg = lane >> 4;

  // bijective XCD swizzle (m204): consecutive wg land on same XCD chunk,
  // so the NS blocks sharing an X segment share an L2.
  const int nwg = gridDim.x, bid = blockIdx.x;
  const int q = nwg >> 3, r = nwg & 7;
  const int xc = bid & 7, li = bid >> 3;
  const int wg = (xc < r ? xc * (q + 1) : r * (q + 1) + (xc - r) * q) + li;
  const int seg = wg / NS, sl = wg % NS;
  const int ch0 = seg * CPS;
  const int ch1 = (ch0 + CPS < 625) ? ch0 + CPS : 625;

  // stage W slice once: 128 rows x 64 slots(16B); linear dest, pre-swz source
#pragma unroll
  for (int i = 0; i < 16; ++i) {
    int e = i * 512 + t;
    int row = e >> 6, slot = e & 63;
    g2lds16(W + (size_t)(sl * 128 + row) * 512 + ((slot ^ (row & 7)) << 3),
            &lds[(i * 512 + wv * 64) * 8 + (lane & 63) * 0 + 0] + (size_t)0 + (size_t)(0));
  }
  // NOTE: dest must be wave-uniform base + lane*16; recompute cleanly:
  // (the expression above simplifies to &lds[e*8] with e = i*512 + t)
  __syncthreads();

  auto LDW = [&](int nt, int ks) -> bf16x8 {
    int row = nt * 16 + lr;
    int byte = row * 1024 + ((ks * 64 + lg * 16) ^ ((row & 7) << 4));
    return *(const bf16x8*)((const char*)lds + byte);
  };

  for (int ch = ch0; ch < ch1; ++ch) {
    const int tokb = ch * 256 + wv * 32;
    // load X fragments for this chunk: 2 token-tiles x 16 k-steps
    bf16x8 xf[2][16];
#pragma unroll
    for (int mt = 0; mt < 2; ++mt)
#pragma unroll
      for (int ks = 0; ks < 16; ++ks)
        xf[mt][ks] = *(const bf16x8*)&X[(size_t)(tokb + mt * 16 + lr) * 512 +
                                        ks * 32 + lg * 8];
    f32x4 acc[2][8];
#pragma unroll
    for (int mt = 0; mt < 2; ++mt)
#pragma unroll
      for (int nt = 0; nt < 8; ++nt) acc[mt][nt] = (f32x4){0.f, 0.f, 0.f, 0.f};

#pragma unroll
    for (int ks = 0; ks < 16; ++ks)
#pragma unroll
      for (int nt = 0; nt < 8; ++nt) {
        bf16x8 wf = LDW(nt, ks);
        acc[0][nt] = __builtin_amdgcn_mfma_f32_16x16x32_bf16(wf, xf[0][ks],
                                                             acc[0][nt], 0, 0, 0);
        acc[1][nt] = __builtin_amdgcn_mfma_f32_16x16x32_bf16(wf, xf[1][ks],
                                                             acc[1][nt], 0, 0, 0);
      }

    if (EPI == 0) {
#pragma unroll
      for (int nt = 0; nt < 8; ++nt) {
        int col = sl * 128 + nt * 16 + lg * 4;
        float4 b4 = *(const float4*)&bias[col];
#pragma unroll
        for (int mt = 0; mt < 2; ++mt) {
          int tok = tokb + mt * 16 + lr;
          uint16_t pk[4];
          pk[0] = f2bf(acc[mt][nt][0] + b4.x);
          pk[1] = f2bf(acc[mt][nt][1] + b4.y);
          pk[2] = f2bf(acc[mt][nt][2] + b4.z);
          pk[3] = f2bf(acc[mt][nt][3] + b4.w);
          uint2 v;
          v.x = (uint32_t)pk[0] | ((uint32_t)pk[1] << 16);
          v.y = (uint32_t)pk[2] | ((uint32_t)pk[3] << 16);
          *(uint2*)&Cbf[(size_t)tok * 1536 + col] = v;
        }
      }
    } else {
      // token -> (g, hh, ww) (window-major); crop hh,ww in [2,98)
      size_t part[2]; bool ok[2];
#pragma unroll
      for (int mt = 0; mt < 2; ++mt) {
        int tok = tokb + mt * 16 + lr;
        int win = tok >> 4, idx = tok & 15;
        int g = win / 625, w2 = win - g * 625;
        int ib = w2 / 25, jb = w2 - ib * 25;
        int hh = ib * 4 + (idx >> 2), ww = jb * 4 + (idx & 3);
        ok[mt] = (hh >= 2) && (hh < 98) && (ww >= 2) && (ww < 98);
        part[mt] = ((size_t)g * 512) * 9216 + (size_t)(hh - 2) * 96 + (ww - 2);
      }
#pragma unroll
      for (int nt = 0; nt < 8; ++nt) {
        int c0 = sl * 128 + nt * 16 + lg * 4;
        float4 b4 = *(const float4*)&bias[c0];
#pragma unroll
        for (int mt = 0; mt < 2; ++mt) {
          if (ok[mt]) {
            Cout[part[mt] + (size_t)(c0 + 0) * 9216] = acc[mt][nt][0] + b4.x;
            Cout[part[mt] + (size_t)(c0 + 1) * 9216] = acc[mt][nt][1] + b4.y;
            Cout[part[mt] + (size_t)(c0 + 2) * 9216] = acc[mt][nt][2] + b4.z;
            Cout[part[mt] + (size_t)(c0 + 3) * 9216] = acc[mt][nt][3] + b4.w;
          }
        }
      }
    }
  }
}

// ---------------------------------------------------------------------------
// Attention: 1 block/window, 128 thr = (head h, query qi). K/V staged in LDS,
// Q read direct. fp32 VALU softmax.
// ---------------------------------------------------------------------------
__global__ __launch_bounds__(128) void attn_kernel(
    const uint16_t* __restrict__ qkv, const float* __restrict__ x,
    uint16_t* __restrict__ obuf, int n0) {
  __shared__ alignas(16) uint16_t skv[16][1024];  // [row][K(512) V(512)]
  __shared__ float smask[16];
  const int b = blockIdx.x;
  const int g = b / 625, wid = b % 625;
  const int ib = wid / 25, jb = wid % 25;
  const int t = threadIdx.x;
  const int wv = t >> 6;
  const int mbase = b * 16;
  const int h = t >> 4, qi = t & 15;

#pragma unroll
  for (int it = 0; it < 16; ++it) {
    int e = it * 128 + t;
    int l = e >> 7, c = e & 127;
    const uint16_t* src = qkv + (size_t)(mbase + l) * 1536 + 512 + c * 8;
    g2lds16(src, (uint16_t*)skv + (it * 128 + wv * 64) * 8);
  }
  float qv[64];
#pragma unroll
  for (int d8 = 0; d8 < 8; ++d8) {
    u16x8 v = *(const u16x8*)&qkv[(size_t)(mbase + qi) * 1536 + h * 64 + d8 * 8];
#pragma unroll
    for (int j = 0; j < 8; ++j) qv[d8 * 8 + j] = bf2f(v[j]);
  }
  if (t < 16) {
    int hh = ib * 4 + (t >> 2), ww = jb * 4 + (t & 3);
    int a = (hh >= 4) ? hh - 4 : hh + 96;
    int c = (ww >= 4) ? ww - 4 : ww + 96;
    smask[t] = (a < 96 && c < 96)
                   ? x[((size_t)(n0 + g) * 512) * 9216 + (size_t)a * 96 + c]
                   : 0.f;
  }
  __syncthreads();

  float s[16];
  float mx = -1e30f;
#pragma unroll
  for (int ki = 0; ki < 16; ++ki) {
    float a = 0.f;
#pragma unroll
    for (int d8 = 0; d8 < 8; ++d8) {
      u16x8 kv = *(const u16x8*)&skv[ki][h * 64 + d8 * 8];
#pragma unroll
      for (int j = 0; j < 8; ++j) a += qv[d8 * 8 + j] * bf2f(kv[j]);
    }
    s[ki] = a * 0.125f + smask[ki];
    mx = fmaxf(mx, s[ki]);
  }
  float sum = 0.f;
#pragma unroll
  for (int ki = 0; ki < 16; ++ki) { s[ki] = __expf(s[ki] - mx); sum += s[ki]; }
  const float inv = 1.f / sum;
  float o[64];
#pragma unroll
  for (int d = 0; d < 64; ++d) o[d] = 0.f;
#pragma unroll
  for (int ki = 0; ki < 16; ++ki) {
    float wgt = s[ki] * inv;
#pragma unroll
    for (int d8 = 0; d8 < 8; ++d8) {
      u16x8 vv = *(const u16x8*)&skv[ki][512 + h * 64 + d8 * 8];
#pragma unroll
      for (int j = 0; j < 8; ++j) o[d8 * 8 + j] += wgt * bf2f(vv[j]);
    }
  }
  const int m = mbase + qi;
#pragma unroll
  for (int d8 = 0; d8 < 8; ++d8) {
    alignas(16) uint16_t tmp[8];
#pragma unroll
    for (int j = 0; j < 8; ++j) tmp[j] = f2bf(o[d8 * 8 + j]);
    *(uint4*)&obuf[(size_t)m * 512 + h * 64 + d8 * 8] = *(uint4*)tmp;
  }
}

// ---------------------------------------------------------------------------
extern "C" void kernel_launch(void* const* d_in, const int* in_sizes, int n_in,
                              void* d_out, int out_size, void* d_ws, size_t ws_size,
                              hipStream_t stream) {
  const float* x  = (const float*)d_in[0];
  const float* wq = (const float*)d_in[1];
  const float* bq = (const float*)d_in[2];
  const float* wo = (const float*)d_in[3];
  const float* bo = (const float*)d_in[4];
  float* out = (float*)d_out;
  uint8_t* ws = (uint8_t*)d_ws;

  uint16_t* wq_bf = (uint16_t*)ws;               // 1.5 MB
  uint16_t* wo_bf = (uint16_t*)(ws + 1572864);   // 0.5 MB
  uint8_t* bufbase = ws + 2097152;

  uint16_t* xo   = (uint16_t*)bufbase;                           // 160000*512 (X, then O)
  uint16_t* qkvb = (uint16_t*)(bufbase + (size_t)160000 * 1024); // 160000*1536
  (void)ws_size;

  cvt_weights<<<dim3(3072), dim3(256), 0, stream>>>(wq, wo, wq_bf, wo_bf);

  gather_kernel<<<dim3(2, 8, 1600), dim3(256), 0, stream>>>(x, xo, 0);
  // qkv[m,1536] = X @ Wqkv^T + b : 12 slices x 21 segments (30 chunks each)
  gemmP<0, 12, 30><<<dim3(252), dim3(512), 0, stream>>>(xo, wq_bf, bq, qkvb, nullptr);
  attn_kernel<<<dim3(10000), dim3(128), 0, stream>>>(qkvb, x, xo, 0);
  // out[c,tok] = Wout @ O^T + b, scatter: 4 slices x 63 segments (10 chunks)
  gemmP<1, 4, 10><<<dim3(252), dim3(512), 0, stream>>>(xo, wo_bf, bo, nullptr, out);

  (void)in_sizes; (void)n_in; (void)out_size;
}